// Round 7
// baseline (297.223 us; speedup 1.0000x reference)
//
#include <hip/hip_runtime.h>

using short8  = __attribute__((ext_vector_type(8))) short;
using ushort8 = __attribute__((ext_vector_type(8))) unsigned short;
using f32x4   = __attribute__((ext_vector_type(4))) float;

#define T 4096
#define E 1024
#define NB 2

__device__ __forceinline__ unsigned short f2bf(float f) {
    unsigned int u = __builtin_bit_cast(unsigned int, f);
    u = (u + 0x7FFFu + ((u >> 16) & 1u)) >> 16;
    return (unsigned short)u;
}

__device__ __forceinline__ void gld16(const unsigned short* g, unsigned short* l) {
    __builtin_amdgcn_global_load_lds(
        (__attribute__((address_space(1))) void*)g,
        (__attribute__((address_space(3))) void*)l, 16, 0, 0);
}

__device__ __forceinline__ void do_cvt(const float* __restrict__ src,
                                       unsigned short* __restrict__ dst, int blk) {
    size_t i = ((size_t)blk * 256 + threadIdx.x) * 8;
    float4 f0 = *(const float4*)(src + i);
    float4 f1 = *(const float4*)(src + i + 4);
    ushort8 u;
    u[0]=f2bf(f0.x); u[1]=f2bf(f0.y); u[2]=f2bf(f0.z); u[3]=f2bf(f0.w);
    u[4]=f2bf(f1.x); u[5]=f2bf(f1.y); u[6]=f2bf(f1.z); u[7]=f2bf(f1.w);
    *(ushort8*)(dst + i) = u;
}

__device__ __forceinline__ void do_vt(const float* __restrict__ v,
                                      unsigned short* __restrict__ vt, int id,
                                      float (*tile)[65]) {
    int b   = id / (64 * 16);
    int rem = id % (64 * 16);
    int t0  = (rem / 16) * 64;
    int e0  = (rem % 16) * 64;
    int tid = threadIdx.x;
    int r   = tid >> 2;
    int c0  = (tid & 3) * 16;
    const float* src = v + ((size_t)(b * T + t0 + r)) * E + e0 + c0;
    #pragma unroll
    for (int i = 0; i < 4; i++) {
        float4 f = *(const float4*)(src + i * 4);
        tile[r][c0 + i*4 + 0] = f.x;
        tile[r][c0 + i*4 + 1] = f.y;
        tile[r][c0 + i*4 + 2] = f.z;
        tile[r][c0 + i*4 + 3] = f.w;
    }
    __syncthreads();
    int er = tid >> 2;
    #pragma unroll
    for (int ch = 0; ch < 2; ch++) {
        int tl = (tid & 3) * 16 + ch * 8;
        ushort8 u;
        #pragma unroll
        for (int j = 0; j < 8; j++) u[j] = f2bf(tile[tl + j][er]);
        *(ushort8*)(vt + ((size_t)(b * E + e0 + er)) * T + t0 + tl) = u;
    }
}

// fused prep: [0,4096) q | [4096,8192) k | [8192,10240) v-transpose | [10240,10272) zero lsum
__global__ __launch_bounds__(256) void prep(const float* __restrict__ q,
                                            const float* __restrict__ k,
                                            const float* __restrict__ v,
                                            unsigned short* __restrict__ qb,
                                            unsigned short* __restrict__ kb,
                                            unsigned short* __restrict__ vt,
                                            float* __restrict__ lsum) {
    __shared__ float tile[64][65];
    int bid = blockIdx.x;
    if (bid < 4096)        do_cvt(q, qb, bid);
    else if (bid < 8192)   do_cvt(k, kb, bid - 4096);
    else if (bid < 10240)  do_vt(v, vt, bid - 8192, tile);
    else                   lsum[(bid - 10240) * 256 + threadIdx.x] = 0.0f;
}

// fallback pieces (aliased-ws path)
__global__ __launch_bounds__(256) void prologue(const float* __restrict__ q,
                                                const float* __restrict__ k,
                                                unsigned short* __restrict__ qb,
                                                unsigned short* __restrict__ kb,
                                                float* __restrict__ lsum) {
    int bid = blockIdx.x;
    if (bid < 4096)      do_cvt(q, qb, bid);
    else if (bid < 8192) do_cvt(k, kb, bid - 4096);
    else                 lsum[(bid - 8192) * 256 + threadIdx.x] = 0.0f;
}
__global__ __launch_bounds__(256) void v_transpose(const float* __restrict__ v,
                                                   unsigned short* __restrict__ vt) {
    __shared__ float tile[64][65];
    do_vt(v, vt, blockIdx.x, tile);
}

// ---------------------------------------------------------------------------
// Shared core: 128x128xBK64, 256 threads (4 waves, 2Mx2N, per-wave 64x64).
// NBUF=2, 64 KB LDS -> 2 blocks/CU. 32 MFMA/wave per barrier pair, only
// 4 waves per barrier. 8-way XOR swizzle, pre-swizzled global source +
// swizzled ds_read offsets. vmcnt(8): current tile landed, next in flight.
// HW-verified in R2 (pass1) and R4 (pass2); best per-FLOP core this session.
// ---------------------------------------------------------------------------
template <int KITERS>
__device__ __forceinline__ void gemm_core64(const unsigned short* Abase, int apitch,
                                            const unsigned short* Bbase, int bpitch,
                                            unsigned short* ldsA, unsigned short* ldsB,
                                            int tid, f32x4 (&acc)[4][4]) {
    constexpr int TILE64 = 128 * 64;         // 8192 ushorts = 16 KB
    const int lane = tid & 63, wave = tid >> 6;
    const int l15 = lane & 15, kq = lane >> 4;
    const int wm = (wave & 1) * 64, wn = (wave >> 1) * 64;

    int goA[4], goB[4], lo[4];
    #pragma unroll
    for (int i = 0; i < 4; i++) {
        int p = i * 256 + tid;               // 1024 chunks of 16B per 128x64 tile
        int r = p >> 3, c = p & 7;
        int sw = c ^ (r & 7);                // inverse-swizzled global chunk
        goA[i] = r * apitch + sw * 8;
        goB[i] = r * bpitch + sw * 8;
        lo[i] = (i * 256 + wave * 64) * 8;   // wave-uniform LDS base (HW adds lane*16B)
    }
    int aoff[2][4], boff[2][4];
    #pragma unroll
    for (int mi = 0; mi < 4; mi++) {
        int r = wm + mi * 16 + l15;
        aoff[0][mi] = (r * 8 + (kq ^ (r & 7))) * 8;
        aoff[1][mi] = (r * 8 + ((kq ^ 4) ^ (r & 7))) * 8;
        int rn = wn + mi * 16 + l15;
        boff[0][mi] = (rn * 8 + (kq ^ (rn & 7))) * 8;
        boff[1][mi] = (rn * 8 + ((kq ^ 4) ^ (rn & 7))) * 8;
    }

    // prologue: tile 0 -> buffer 0 (8 loads outstanding)
    #pragma unroll
    for (int i = 0; i < 4; i++) gld16(Abase + goA[i], ldsA + lo[i]);
    #pragma unroll
    for (int i = 0; i < 4; i++) gld16(Bbase + goB[i], ldsB + lo[i]);

    int cbuf = 0;
    for (int kt = 0; kt < KITERS; kt++) {
        int pk = (kt + 1 < KITERS) ? (kt + 1) : 0;   // tail reload is harmless
        int ob = cbuf ^ 1;
        asm volatile("s_barrier" ::: "memory");      // all waves done reading buf ob
        #pragma unroll
        for (int i = 0; i < 4; i++) gld16(Abase + goA[i] + pk * 64, ldsA + ob * TILE64 + lo[i]);
        #pragma unroll
        for (int i = 0; i < 4; i++) gld16(Bbase + goB[i] + pk * 64, ldsB + ob * TILE64 + lo[i]);
        asm volatile("s_waitcnt vmcnt(8)" ::: "memory");  // tile kt landed; kt+1 in flight
        asm volatile("s_barrier" ::: "memory");

        const unsigned short* A = ldsA + cbuf * TILE64;
        const unsigned short* B = ldsB + cbuf * TILE64;
        #pragma unroll
        for (int ks = 0; ks < 2; ks++) {
            short8 af[4], bf[4];
            #pragma unroll
            for (int i = 0; i < 4; i++) {
                af[i] = *(const short8*)(A + aoff[ks][i]);
                bf[i] = *(const short8*)(B + boff[ks][i]);
            }
            #pragma unroll
            for (int mi = 0; mi < 4; mi++)
                #pragma unroll
                for (int ni = 0; ni < 4; ni++)
                    acc[mi][ni] = __builtin_amdgcn_mfma_f32_16x16x32_bf16(af[mi], bf[ni], acc[mi][ni], 0, 0, 0);
        }
        cbuf = ob;
    }
}

// Pass 1: P = exp2(scale*log2e*(Q K^T) - 12) [bf16], lsum += row sums [fp32]
// 128x128 tile, 2048 blocks. Supertile swizzle: XCD xc owns gm rows
// [xc*8, xc*8+8); within an XCD, blocks iterate in 8gm x 8nt supertiles
// (64 blocks = 8 q-panels + 8 k-panels = 4 MB = one XCD L2).
__global__ __launch_bounds__(256, 2) void pass1(const unsigned short* __restrict__ qb,
                                                const unsigned short* __restrict__ kb,
                                                unsigned short* __restrict__ P,
                                                float* __restrict__ lsum) {
    constexpr int TILE64 = 128 * 64;
    __shared__ unsigned short ldsA[2 * TILE64];  // 32 KB
    __shared__ unsigned short ldsB[2 * TILE64];  // 32 KB

    const int bx  = blockIdx.x;
    const int xc  = bx & 7;                          // XCD
    const int sj  = bx >> 3;                         // [0,256) per XCD
    const int gm  = xc * 8 + (sj & 7);               // [0,64): b*32+mt
    const int nt  = ((sj >> 6) << 3) + ((sj >> 3) & 7);  // [0,32)
    const int b   = gm >> 5, mt = gm & 31;
    const int tid = threadIdx.x;

    f32x4 acc[4][4];
    #pragma unroll
    for (int i = 0; i < 4; i++)
        #pragma unroll
        for (int jj = 0; jj < 4; jj++) acc[i][jj] = {};

    gemm_core64<E / 64>(qb + ((size_t)b * T + mt * 128) * E, E,
                        kb + ((size_t)b * T + nt * 128) * E, E,
                        ldsA, ldsB, tid, acc);

    const int lane = tid & 63, wave = tid >> 6;
    const int wm = (wave & 1) * 64, wn = (wave >> 1) * 64;
    const int quad = lane >> 4, l15 = lane & 15;
    const float sl2 = 0.0625f * 1.44269504089f;
    const int col0 = nt * 128 + wn + l15;

    #pragma unroll
    for (int mi = 0; mi < 4; mi++) {
        #pragma unroll
        for (int r = 0; r < 4; r++) {
            int row = mt * 128 + wm + mi * 16 + quad * 4 + r;
            size_t base = ((size_t)b * T + row) * T + col0;
            float rs = 0.0f;
            #pragma unroll
            for (int ni = 0; ni < 4; ni++) {
                float p = exp2f(acc[mi][ni][r] * sl2 - 12.0f);
                P[base + ni * 16] = f2bf(p);
                rs += p;
            }
            rs += __shfl_xor(rs, 1);
            rs += __shfl_xor(rs, 2);
            rs += __shfl_xor(rs, 4);
            rs += __shfl_xor(rs, 8);
            if (l15 == 0) atomicAdd(lsum + b * T + row, rs);
        }
    }
}

// Pass 2: O = (P @ V) / l ; B operand = VT [b][e][t]
__global__ __launch_bounds__(256, 2) void pass2(const unsigned short* __restrict__ P,
                                                const unsigned short* __restrict__ vt,
                                                const float* __restrict__ lsum,
                                                float* __restrict__ out) {
    constexpr int TILE64 = 128 * 64;
    __shared__ unsigned short ldsA[2 * TILE64];  // 32 KB
    __shared__ unsigned short ldsB[2 * TILE64];  // 32 KB

    const int bx = blockIdx.x;
    const int xc = bx & 7, j = bx >> 3;      // j in [0,64)
    const int gm = xc * 8 + (j & 7);         // [0,64): b*32+mt
    const int nt = j >> 3;                   // [0,8)
    const int b = gm >> 5, mt = gm & 31;
    const int tid = threadIdx.x;

    f32x4 acc[4][4];
    #pragma unroll
    for (int i = 0; i < 4; i++)
        #pragma unroll
        for (int jj = 0; jj < 4; jj++) acc[i][jj] = {};

    gemm_core64<T / 64>(P + ((size_t)b * T + mt * 128) * T, T,
                        vt + ((size_t)b * E + nt * 128) * T, T,
                        ldsA, ldsB, tid, acc);

    const int lane = tid & 63, wave = tid >> 6;
    const int wm = (wave & 1) * 64, wn = (wave >> 1) * 64;
    const int quad = lane >> 4, l15 = lane & 15;
    const int col0 = nt * 128 + wn + l15;

    #pragma unroll
    for (int mi = 0; mi < 4; mi++) {
        #pragma unroll
        for (int r = 0; r < 4; r++) {
            int row = mt * 128 + wm + mi * 16 + quad * 4 + r;
            float rl = 1.0f / lsum[b * T + row];
            size_t base = ((size_t)b * T + row) * E + col0;
            #pragma unroll
            for (int ni = 0; ni < 4; ni++)
                out[base + ni * 16] = acc[mi][ni][r] * rl;
        }
    }
}

extern "C" void kernel_launch(void* const* d_in, const int* in_sizes, int n_in,
                              void* d_out, int out_size, void* d_ws, size_t ws_size,
                              hipStream_t stream) {
    const float* q = (const float*)d_in[0];
    const float* k = (const float*)d_in[1];
    const float* v = (const float*)d_in[2];
    float* out = (float*)d_out;

    const size_t QK = (size_t)NB * T * E;
    const size_t PSZ = (size_t)NB * T * T;
    float* lsum = (float*)d_ws;
    unsigned short* qbw = (unsigned short*)((char*)d_ws + 32768);
    unsigned short* kbw = qbw + QK;
    unsigned short* Pw  = kbw + QK;

    const size_t full_need = 32768 + (3 * QK + PSZ) * sizeof(unsigned short);

    if (ws_size >= full_need) {
        unsigned short* vtw = Pw + PSZ;
        prep<<<10272, 256, 0, stream>>>(q, k, v, qbw, kbw, vtw, lsum);
        pass1<<<2048, 256, 0, stream>>>(qbw, kbw, Pw, lsum);
        pass2<<<512, 256, 0, stream>>>(Pw, vtw, lsum, out);
    } else {
        unsigned short* vtw = qbw;
        prologue<<<8224, 256, 0, stream>>>(q, k, qbw, kbw, lsum);
        pass1<<<2048, 256, 0, stream>>>(qbw, kbw, Pw, lsum);
        v_transpose<<<NB * 64 * 16, 256, 0, stream>>>(v, vtw);
        pass2<<<512, 256, 0, stream>>>(Pw, vtw, lsum, out);
    }
}